// Round 1
// baseline (589.708 us; speedup 1.0000x reference)
//
#include <hip/hip_runtime.h>
#include <hip/hip_bf16.h>
#include <math.h>

#define NTOK 131072
#define DIM  256
#define EDIM 512
#define NB   16
#define NL   64
#define NSEG (NB*NL)    // 1024
#define K3D  768        // 3*DIM
#define K2D  512        // 2*DIM

typedef __attribute__((ext_vector_type(8))) short short8;
typedef __attribute__((ext_vector_type(4))) float f32x4;

// monotone float<->uint code so atomicMax(uint) == float max
static __device__ __forceinline__ unsigned fcode(float x){
  unsigned b = __float_as_uint(x);
  return (b & 0x80000000u) ? ~b : (b | 0x80000000u);
}
static __device__ __forceinline__ float fdecode(unsigned c){
  unsigned b = (c & 0x80000000u) ? (c ^ 0x80000000u) : ~c;
  return __uint_as_float(b);
}
#define NEG_INF_CODE 0x007FFFFFu   // fcode(-inf)

static __device__ __forceinline__ short f2bf(float x){
  union { __hip_bfloat16 h; short s; } u; u.h = __float2bfloat16(x); return u.s;
}

// ---------------- K0: init accumulators ----------------
__global__ __launch_bounds__(256) void k0_init(float* sums, unsigned* maxc, float* attn,
                                               int* counts, unsigned* bmax){
  int i = blockIdx.x*256 + threadIdx.x;
  if (i < NSEG*DIM){ sums[i]=0.f; attn[i]=0.f; maxc[i]=NEG_INF_CODE; }
  if (i < NSEG) counts[i]=0;
  if (i < NB)   bmax[i]=NEG_INF_CODE;
}

// ---------------- K0t: transpose+convert weights to bf16 [N][K] ----------------
__global__ __launch_bounds__(256) void k0_transpose(const float* __restrict__ W1, const float* __restrict__ W2,
                                                    const float* __restrict__ Wc,
                                                    short* __restrict__ W1t, short* __restrict__ W2t,
                                                    short* __restrict__ Wct){
  __shared__ short tile[64][65];
  int b = blockIdx.x;
  const float* src; short* dst; int K, N, kt, nt;
  if (b < 96){ src=W1; dst=W1t; K=768; N=512; kt=b/8;  nt=b%8;  }
  else if (b < 128){ int c=b-96;  src=W2; dst=W2t; K=512; N=256; kt=c/4; nt=c%4; }
  else             { int c=b-128; src=Wc; dst=Wct; K=512; N=256; kt=c/4; nt=c%4; }
  int k0 = kt*64, n0 = nt*64;
  for (int e = threadIdx.x; e < 4096; e += 256){
    int r = e >> 6, c = e & 63;                       // r: k-row, c: n-col (coalesced read)
    tile[c][r] = f2bf(src[(size_t)(k0+r)*N + n0 + c]);
  }
  __syncthreads();
  for (int e = threadIdx.x; e < 4096; e += 256){
    int r = e >> 6, c = e & 63;                       // r: n-row, c: k-col (coalesced write)
    dst[(size_t)(n0+r)*K + k0 + c] = tile[r][c];
  }
}

// ---------------- K1: logits, seg ids, per-batch max ----------------
__global__ __launch_bounds__(256) void k1_logits(const float* __restrict__ feats, const int* __restrict__ cu,
    const int* __restrict__ layer_ids, const float* __restrict__ Wa, const float* __restrict__ ba,
    float* __restrict__ logits, int* __restrict__ seg, unsigned* __restrict__ bmax){
  int wave = threadIdx.x >> 6, lane = threadIdx.x & 63;
  int t0 = blockIdx.x*64 + wave*16;
  float4 wa = *(const float4*)(Wa + lane*4);
  float bav = ba[0];
  float wmax = -INFINITY; int wbatch = -1;
  for (int k = 0; k < 16; ++k){
    int i = t0 + k;
    float4 x = *(const float4*)(feats + (size_t)i*DIM + lane*4);
    float p = x.x*wa.x + x.y*wa.y + x.z*wa.z + x.w*wa.w;
    for (int off = 32; off; off >>= 1) p += __shfl_xor(p, off);
    if (lane == 0){
      float lg = p + bav;
      logits[i] = lg;
      int b = 0;
      for (int j = 1; j <= NB; ++j){ if (cu[j] <= i) b = j; else break; }
      seg[i] = b*NL + layer_ids[i];
      if (b != wbatch){
        if (wbatch >= 0) atomicMax(&bmax[wbatch], fcode(wmax));
        wbatch = b; wmax = lg;
      } else wmax = fmaxf(wmax, lg);
    }
  }
  if (lane == 0 && wbatch >= 0) atomicMax(&bmax[wbatch], fcode(wmax));
}

// ---------------- K2: exp + per-batch Z (deterministic tree) ----------------
__global__ __launch_bounds__(256) void k2_softmax_z(const float* __restrict__ logits, const int* __restrict__ cu,
    const unsigned* __restrict__ bmax, float* __restrict__ evals, float* __restrict__ bz){
  __shared__ float red[256];
  int b = blockIdx.x;
  int s = cu[b], e = cu[b+1];
  float m = fdecode(bmax[b]);
  float acc = 0.f;
  for (int i = s + threadIdx.x; i < e; i += 256){
    float ev = expf(logits[i] - m);
    evals[i] = ev; acc += ev;
  }
  red[threadIdx.x] = acc; __syncthreads();
  for (int off = 128; off; off >>= 1){
    if (threadIdx.x < off) red[threadIdx.x] += red[threadIdx.x + off];
    __syncthreads();
  }
  if (threadIdx.x == 0) bz[b] = red[0];
}

// ---------------- K3: segmented avg/max/attn pooling ----------------
// grid: 16 batches x 8 dim-chunks(32) x 8 token-eighths = 1024 blocks
__global__ __launch_bounds__(256) void k3_pool(const float* __restrict__ feats, const int* __restrict__ cu,
    const int* __restrict__ layer_ids, const float* __restrict__ evals, const float* __restrict__ bz,
    float* __restrict__ sums, unsigned* __restrict__ maxc, float* __restrict__ attn, int* __restrict__ counts){
  __shared__ float    lsum[NL*33];
  __shared__ unsigned lmax[NL*33];
  __shared__ float    latt[NL*33];
  __shared__ int      lcnt[NL];
  int blk = blockIdx.x;
  int b  = blk >> 6;
  int dc = (blk >> 3) & 7;
  int e8 = blk & 7;
  for (int i = threadIdx.x; i < NL*33; i += 256){ lsum[i]=0.f; latt[i]=0.f; lmax[i]=NEG_INF_CODE; }
  if (threadIdx.x < NL) lcnt[threadIdx.x] = 0;
  __syncthreads();
  int s = cu[b], e = cu[b+1], len = e - s;
  int t0 = s + (int)(((long long)len * e8) >> 3);
  int t1 = s + (int)(((long long)len * (e8+1)) >> 3);
  float invz = 1.0f / bz[b];
  int f4 = threadIdx.x & 7;
  int dbase = dc*32 + f4*4;
  for (int tok = t0 + (threadIdx.x >> 3); tok < t1; tok += 32){
    float4 x = *(const float4*)(feats + (size_t)tok*DIM + dbase);
    int l = layer_ids[tok];
    float w = evals[tok] * invz;
    int base = l*33 + f4*4;
    atomicAdd(&lsum[base+0], x.x); atomicAdd(&lsum[base+1], x.y);
    atomicAdd(&lsum[base+2], x.z); atomicAdd(&lsum[base+3], x.w);
    atomicMax(&lmax[base+0], fcode(x.x)); atomicMax(&lmax[base+1], fcode(x.y));
    atomicMax(&lmax[base+2], fcode(x.z)); atomicMax(&lmax[base+3], fcode(x.w));
    atomicAdd(&latt[base+0], x.x*w); atomicAdd(&latt[base+1], x.y*w);
    atomicAdd(&latt[base+2], x.z*w); atomicAdd(&latt[base+3], x.w*w);
    if (dc == 0 && f4 == 0) atomicAdd(&lcnt[l], 1);
  }
  __syncthreads();
  for (int i = threadIdx.x; i < NL*32; i += 256){
    int l = i >> 5, d = i & 31;
    size_t g = (size_t)(b*NL + l)*DIM + dc*32 + d;
    atomicAdd(&sums[g], lsum[l*33+d]);
    atomicMax(&maxc[g], lmax[l*33+d]);
    atomicAdd(&attn[g], latt[l*33+d]);
  }
  if (dc == 0){
    for (int l = threadIdx.x; l < NL; l += 256) atomicAdd(&counts[b*NL + l], lcnt[l]);
  }
}

// ---------------- K4p: assemble pooled [1024][768] in bf16 ----------------
__global__ __launch_bounds__(256) void k4_pooled(const float* __restrict__ sums, const unsigned* __restrict__ maxc,
    const float* __restrict__ attn, const int* __restrict__ counts, short* __restrict__ pooledb){
  int i = blockIdx.x*256 + threadIdx.x;      // over NSEG*DIM
  int sgi = i >> 8, d = i & 255;
  int cnt = counts[sgi];
  float inv = 1.0f / (float)(cnt > 1 ? cnt : 1);
  float avg = sums[i] * inv;
  float mx  = cnt > 0 ? fdecode(maxc[i]) : 0.f;
  float at  = attn[i];
  size_t rb = (size_t)sgi * K3D;
  pooledb[rb + d]         = f2bf(avg);
  pooledb[rb + DIM + d]   = f2bf(mx);
  pooledb[rb + 2*DIM + d] = f2bf(at);
}

// ---------------- small MFMA GEMM: C[M,N] = act(A[M,K] @ Bt[N,K]^T + bias) -> bf16 ----------------
template<int GELU>
__global__ __launch_bounds__(256) void gemm64(const short* __restrict__ A, const short* __restrict__ Bt,
    const float* __restrict__ bias, short* __restrict__ Cout, int K, int ldc){
  __shared__ short lA[64][40];
  __shared__ short lB[64][40];
  int tid = threadIdx.x;
  int wave = tid >> 6, lane = tid & 63;
  int wm = wave >> 1, wn = wave & 1;
  int rb = blockIdx.x * 64, cb = blockIdx.y * 64;
  int l15 = lane & 15, lg = lane >> 4;
  f32x4 acc[2][2] = {};
  int srow = tid >> 2, skg = tid & 3;
  for (int ks = 0; ks < K; ks += 32){
    __syncthreads();
    *(short8*)&lA[srow][skg*8] = *(const short8*)(A  + (size_t)(rb+srow)*K + ks + skg*8);
    *(short8*)&lB[srow][skg*8] = *(const short8*)(Bt + (size_t)(cb+srow)*K + ks + skg*8);
    __syncthreads();
    short8 af[2], bf[2];
#pragma unroll
    for (int f = 0; f < 2; ++f){
      af[f] = *(const short8*)&lA[wm*32 + f*16 + l15][lg*8];
      bf[f] = *(const short8*)&lB[wn*32 + f*16 + l15][lg*8];
    }
#pragma unroll
    for (int fm = 0; fm < 2; ++fm)
#pragma unroll
      for (int fn = 0; fn < 2; ++fn)
        acc[fm][fn] = __builtin_amdgcn_mfma_f32_16x16x32_bf16(af[fm], bf[fn], acc[fm][fn], 0, 0, 0);
  }
#pragma unroll
  for (int fm = 0; fm < 2; ++fm)
#pragma unroll
    for (int fn = 0; fn < 2; ++fn){
      int col = cb + wn*32 + fn*16 + l15;
      float bcv = bias[col];
#pragma unroll
      for (int r = 0; r < 4; ++r){
        int row = rb + wm*32 + fm*16 + lg*4 + r;
        float v = acc[fm][fn][r] + bcv;
        if (GELU) v = 0.5f * v * (1.0f + erff(v * 0.70710678118f));
        Cout[(size_t)row*ldc + col] = f2bf(v);
      }
    }
}

// ---------------- K5: out = [gather(lf, seg) | feats] @ Wc + bc ----------------
// block: 128 rows x 256 cols (full N), 8 waves (2x4), wave tile 64x64 = 4x4 frags
__global__ __launch_bounds__(512) void k5_final(const float* __restrict__ feats, const short* __restrict__ lfb,
    const int* __restrict__ seg, const short* __restrict__ Wct, const float* __restrict__ bc,
    float* __restrict__ out){
  __shared__ short lA[128][72];
  __shared__ short lB[256][72];
  int tid = threadIdx.x;
  int wave = tid >> 6, lane = tid & 63;
  int wm = wave >> 2, wn = wave & 3;
  int rb = blockIdx.x * 128;
  int l15 = lane & 15, lg = lane >> 4;
  f32x4 acc[4][4] = {};
  for (int ks = 0; ks < 8; ++ks){
    __syncthreads();
    // stage A: 128 rows x 64 k (bf16). k<256 -> gathered layer_feats; k>=256 -> feats (f32->bf16)
#pragma unroll
    for (int i = 0; i < 2; ++i){
      int slot = tid + i*512;
      int row = slot >> 3, kg = slot & 7;
      short8 v;
      if (ks < 4){
        int sg = seg[rb + row];
        v = *(const short8*)(lfb + (size_t)sg*DIM + ks*64 + kg*8);
      } else {
        const float* fp = feats + (size_t)(rb+row)*DIM + (ks-4)*64 + kg*8;
        float4 u0 = *(const float4*)fp;
        float4 u1 = *(const float4*)(fp+4);
        short8 t;
        t[0]=f2bf(u0.x); t[1]=f2bf(u0.y); t[2]=f2bf(u0.z); t[3]=f2bf(u0.w);
        t[4]=f2bf(u1.x); t[5]=f2bf(u1.y); t[6]=f2bf(u1.z); t[7]=f2bf(u1.w);
        v = t;
      }
      *(short8*)&lA[row][kg*8] = v;
    }
    // stage B: 256 n-rows x 64 k from Wct [256][512]
#pragma unroll
    for (int i = 0; i < 4; ++i){
      int slot = tid + i*512;
      int n = slot >> 3, kg = slot & 7;
      *(short8*)&lB[n][kg*8] = *(const short8*)(Wct + (size_t)n*K2D + ks*64 + kg*8);
    }
    __syncthreads();
#pragma unroll
    for (int kk = 0; kk < 2; ++kk){
      short8 af[4], bf[4];
#pragma unroll
      for (int f = 0; f < 4; ++f){
        af[f] = *(const short8*)&lA[wm*64 + f*16 + l15][kk*32 + lg*8];
        bf[f] = *(const short8*)&lB[wn*64 + f*16 + l15][kk*32 + lg*8];
      }
#pragma unroll
      for (int fm = 0; fm < 4; ++fm)
#pragma unroll
        for (int fn = 0; fn < 4; ++fn)
          acc[fm][fn] = __builtin_amdgcn_mfma_f32_16x16x32_bf16(af[fm], bf[fn], acc[fm][fn], 0, 0, 0);
    }
  }
#pragma unroll
  for (int fm = 0; fm < 4; ++fm)
#pragma unroll
    for (int fn = 0; fn < 4; ++fn){
      int col = wn*64 + fn*16 + l15;
      float bcv = bc[col];
#pragma unroll
      for (int r = 0; r < 4; ++r){
        int row = rb + wm*64 + fm*16 + lg*4 + r;
        out[(size_t)row*DIM + col] = acc[fm][fn][r] + bcv;
      }
    }
}

extern "C" void kernel_launch(void* const* d_in, const int* in_sizes, int n_in,
                              void* d_out, int out_size, void* d_ws, size_t ws_size,
                              hipStream_t stream){
  const float* feats     = (const float*)d_in[0];
  const int*   cu        = (const int*)d_in[1];
  const int*   layer_ids = (const int*)d_in[2];
  const float* Wa        = (const float*)d_in[3];
  const float* ba        = (const float*)d_in[4];
  const float* W1        = (const float*)d_in[5];
  const float* b1        = (const float*)d_in[6];
  const float* W2        = (const float*)d_in[7];
  const float* b2        = (const float*)d_in[8];
  const float* Wc        = (const float*)d_in[9];
  const float* bc        = (const float*)d_in[10];
  float* out = (float*)d_out;

  char* w = (char*)d_ws;
  auto alloc = [&](size_t bytes)->char*{ char* p = w; w += (bytes + 255) & ~255ull; return p; };
  float*    logits  = (float*)   alloc((size_t)NTOK*4);
  float*    evals   = (float*)   alloc((size_t)NTOK*4);
  int*      seg     = (int*)     alloc((size_t)NTOK*4);
  unsigned* bmax    = (unsigned*)alloc(NB*4);
  float*    bz      = (float*)   alloc(NB*4);
  int*      counts  = (int*)     alloc(NSEG*4);
  float*    sums    = (float*)   alloc((size_t)NSEG*DIM*4);
  unsigned* maxc    = (unsigned*)alloc((size_t)NSEG*DIM*4);
  float*    attn    = (float*)   alloc((size_t)NSEG*DIM*4);
  short*    W1t     = (short*)   alloc((size_t)512*768*2);
  short*    W2t     = (short*)   alloc((size_t)256*512*2);
  short*    Wct     = (short*)   alloc((size_t)256*512*2);
  short*    pooledb = (short*)   alloc((size_t)NSEG*K3D*2);
  short*    hb      = (short*)   alloc((size_t)NSEG*EDIM*2);
  short*    lfb     = (short*)   alloc((size_t)NSEG*DIM*2);

  k0_init<<<dim3(1024), dim3(256), 0, stream>>>(sums, maxc, attn, counts, bmax);
  k0_transpose<<<dim3(160), dim3(256), 0, stream>>>(W1, W2, Wc, W1t, W2t, Wct);
  k1_logits<<<dim3(2048), dim3(256), 0, stream>>>(feats, cu, layer_ids, Wa, ba, logits, seg, bmax);
  k2_softmax_z<<<dim3(16), dim3(256), 0, stream>>>(logits, cu, bmax, evals, bz);
  k3_pool<<<dim3(1024), dim3(256), 0, stream>>>(feats, cu, layer_ids, evals, bz, sums, maxc, attn, counts);
  k4_pooled<<<dim3(1024), dim3(256), 0, stream>>>(sums, maxc, attn, counts, pooledb);
  gemm64<1><<<dim3(16, 8), dim3(256), 0, stream>>>(pooledb, W1t, b1, hb, 768, 512);
  gemm64<0><<<dim3(16, 4), dim3(256), 0, stream>>>(hb, W2t, b2, lfb, 512, 256);
  k5_final<<<dim3(1024), dim3(512), 0, stream>>>(feats, lfb, seg, Wct, bc, out);
}

// Round 2
// 310.889 us; speedup vs baseline: 1.8968x; 1.8968x over previous
//
#include <hip/hip_runtime.h>
#include <hip/hip_bf16.h>
#include <math.h>

#define NTOK 131072
#define DIM  256
#define EDIM 512
#define NB   16
#define NL   64
#define NSEG (NB*NL)    // 1024
#define K3D  768        // 3*DIM
#define K2D  512        // 2*DIM
#define HB   64         // histogram/scatter blocks (2048 tokens each)

typedef __attribute__((ext_vector_type(8))) short short8;
typedef __attribute__((ext_vector_type(4))) float f32x4;

// monotone float<->uint code so atomicMax(uint) == float max
static __device__ __forceinline__ unsigned fcode(float x){
  unsigned b = __float_as_uint(x);
  return (b & 0x80000000u) ? ~b : (b | 0x80000000u);
}
static __device__ __forceinline__ float fdecode(unsigned c){
  unsigned b = (c & 0x80000000u) ? (c ^ 0x80000000u) : ~c;
  return __uint_as_float(b);
}
#define NEG_INF_CODE 0x007FFFFFu   // fcode(-inf)

static __device__ __forceinline__ short f2bf(float x){
  union { __hip_bfloat16 h; short s; } u; u.h = __float2bfloat16(x); return u.s;
}

// ---------------- K0t: transpose+convert weights to bf16 [N][K]; also init bmax ----------------
__global__ __launch_bounds__(256) void k0_transpose(const float* __restrict__ W1, const float* __restrict__ W2,
                                                    const float* __restrict__ Wc,
                                                    short* __restrict__ W1t, short* __restrict__ W2t,
                                                    short* __restrict__ Wct, unsigned* __restrict__ bmax){
  if (blockIdx.x == 0 && threadIdx.x < NB) bmax[threadIdx.x] = NEG_INF_CODE;
  __shared__ short tile[64][65];
  int b = blockIdx.x;
  const float* src; short* dst; int K, N, kt, nt;
  if (b < 96){ src=W1; dst=W1t; K=768; N=512; kt=b/8;  nt=b%8;  }
  else if (b < 128){ int c=b-96;  src=W2; dst=W2t; K=512; N=256; kt=c/4; nt=c%4; }
  else             { int c=b-128; src=Wc; dst=Wct; K=512; N=256; kt=c/4; nt=c%4; }
  int k0 = kt*64, n0 = nt*64;
  for (int e = threadIdx.x; e < 4096; e += 256){
    int r = e >> 6, c = e & 63;                       // r: k-row, c: n-col (coalesced read)
    tile[c][r] = f2bf(src[(size_t)(k0+r)*N + n0 + c]);
  }
  __syncthreads();
  for (int e = threadIdx.x; e < 4096; e += 256){
    int r = e >> 6, c = e & 63;                       // r: n-row, c: k-col (coalesced write)
    dst[(size_t)(n0+r)*K + k0 + c] = tile[r][c];
  }
}

// ---------------- K1: logits, seg ids, per-batch max ----------------
__global__ __launch_bounds__(256) void k1_logits(const float* __restrict__ feats, const int* __restrict__ cu,
    const int* __restrict__ layer_ids, const float* __restrict__ Wa, const float* __restrict__ ba,
    float* __restrict__ logits, int* __restrict__ seg, unsigned* __restrict__ bmax){
  int wave = threadIdx.x >> 6, lane = threadIdx.x & 63;
  int t0 = blockIdx.x*64 + wave*16;
  float4 wa = *(const float4*)(Wa + lane*4);
  float bav = ba[0];
  float wmax = -INFINITY; int wbatch = -1;
  for (int k = 0; k < 16; ++k){
    int i = t0 + k;
    float4 x = *(const float4*)(feats + (size_t)i*DIM + lane*4);
    float p = x.x*wa.x + x.y*wa.y + x.z*wa.z + x.w*wa.w;
    for (int off = 32; off; off >>= 1) p += __shfl_xor(p, off);
    if (lane == 0){
      float lg = p + bav;
      logits[i] = lg;
      int b = 0;
      for (int j = 1; j <= NB; ++j){ if (cu[j] <= i) b = j; else break; }
      seg[i] = b*NL + layer_ids[i];
      if (b != wbatch){
        if (wbatch >= 0) atomicMax(&bmax[wbatch], fcode(wmax));
        wbatch = b; wmax = lg;
      } else wmax = fmaxf(wmax, lg);
    }
  }
  if (lane == 0 && wbatch >= 0) atomicMax(&bmax[wbatch], fcode(wmax));
}

// ---------------- K2: exp + per-batch Z (deterministic tree) ----------------
__global__ __launch_bounds__(256) void k2_softmax_z(const float* __restrict__ logits, const int* __restrict__ cu,
    const unsigned* __restrict__ bmax, float* __restrict__ evals, float* __restrict__ bz){
  __shared__ float red[256];
  int b = blockIdx.x;
  int s = cu[b], e = cu[b+1];
  float m = fdecode(bmax[b]);
  float acc = 0.f;
  for (int i = s + threadIdx.x; i < e; i += 256){
    float ev = expf(logits[i] - m);
    evals[i] = ev; acc += ev;
  }
  red[threadIdx.x] = acc; __syncthreads();
  for (int off = 128; off; off >>= 1){
    if (threadIdx.x < off) red[threadIdx.x] += red[threadIdx.x + off];
    __syncthreads();
  }
  if (threadIdx.x == 0) bz[b] = red[0];
}

// ---------------- K3a: per-block segment histogram ----------------
__global__ __launch_bounds__(256) void k3a_hist(const int* __restrict__ seg, int* __restrict__ hist){
  __shared__ int h[NSEG];
  for (int i = threadIdx.x; i < NSEG; i += 256) h[i] = 0;
  __syncthreads();
  int base = blockIdx.x * (NTOK/HB);
  for (int i = threadIdx.x; i < NTOK/HB; i += 256) atomicAdd(&h[seg[base+i]], 1);
  __syncthreads();
  for (int i = threadIdx.x; i < NSEG; i += 256) hist[i*HB + blockIdx.x] = h[i];
}

// ---------------- K3b: scan -> per-(seg,block) offsets + segstart ----------------
__global__ __launch_bounds__(1024) void k3b_scan(int* __restrict__ hist, int* __restrict__ segstart){
  __shared__ int sc[NSEG];
  int s = threadIdx.x;
  int base = s*HB;
  int tot = 0;
#pragma unroll
  for (int b = 0; b < HB; ++b) tot += hist[base+b];
  sc[s] = tot; __syncthreads();
  for (int off = 1; off < NSEG; off <<= 1){
    int v = (s >= off) ? sc[s-off] : 0;
    __syncthreads();
    sc[s] += v;
    __syncthreads();
  }
  int segbase = sc[s] - tot;   // exclusive prefix
  segstart[s] = segbase;
  if (s == 0) segstart[NSEG] = NTOK;
  int run = segbase;
#pragma unroll
  for (int b = 0; b < HB; ++b){ int c = hist[base+b]; hist[base+b] = run; run += c; }
}

// ---------------- K3c: stable-ish scatter of token ids by segment ----------------
__global__ __launch_bounds__(256) void k3c_scatter(const int* __restrict__ seg, const int* __restrict__ hist,
                                                   int* __restrict__ sorted){
  __shared__ int cur[NSEG];
  for (int i = threadIdx.x; i < NSEG; i += 256) cur[i] = hist[i*HB + blockIdx.x];
  __syncthreads();
  int base = blockIdx.x * (NTOK/HB);
  for (int i = threadIdx.x; i < NTOK/HB; i += 256){
    int sg = seg[base+i];
    int p = atomicAdd(&cur[sg], 1);
    sorted[p] = base+i;
  }
}

// ---------------- K4: segmented reduce over sorted tokens -> pooled [1024][768] bf16 ----------------
__global__ __launch_bounds__(256) void k4_pool(const float* __restrict__ feats, const int* __restrict__ sorted,
    const int* __restrict__ segstart, const float* __restrict__ evals, const float* __restrict__ bz,
    short* __restrict__ pooledb){
  __shared__ float redS[4][DIM];
  __shared__ float redM[4][DIM];
  __shared__ float redA[4][DIM];
  int sgi = blockIdx.x;
  int b = sgi >> 6;
  int s = segstart[sgi], e = segstart[sgi+1];
  int cnt = e - s;
  float invz = 1.0f / bz[b];
  int lane = threadIdx.x & 63, grp = threadIdx.x >> 6;
  float4 sum = make_float4(0.f,0.f,0.f,0.f), att = make_float4(0.f,0.f,0.f,0.f);
  float4 mx  = make_float4(-INFINITY,-INFINITY,-INFINITY,-INFINITY);
  for (int i = s + grp; i < e; i += 4){
    int tok = sorted[i];
    float4 x = *(const float4*)(feats + (size_t)tok*DIM + lane*4);
    float w = evals[tok] * invz;
    sum.x += x.x; sum.y += x.y; sum.z += x.z; sum.w += x.w;
    mx.x = fmaxf(mx.x, x.x); mx.y = fmaxf(mx.y, x.y);
    mx.z = fmaxf(mx.z, x.z); mx.w = fmaxf(mx.w, x.w);
    att.x += x.x*w; att.y += x.y*w; att.z += x.z*w; att.w += x.w*w;
  }
  *(float4*)&redS[grp][lane*4] = sum;
  *(float4*)&redM[grp][lane*4] = mx;
  *(float4*)&redA[grp][lane*4] = att;
  __syncthreads();
  int d = threadIdx.x;
  float rs = redS[0][d] + redS[1][d] + redS[2][d] + redS[3][d];
  float rm = fmaxf(fmaxf(redM[0][d], redM[1][d]), fmaxf(redM[2][d], redM[3][d]));
  float ra = redA[0][d] + redA[1][d] + redA[2][d] + redA[3][d];
  float inv = 1.0f / (float)(cnt > 1 ? cnt : 1);
  size_t rb_ = (size_t)sgi * K3D;
  pooledb[rb_ + d]         = f2bf(rs * inv);
  pooledb[rb_ + DIM + d]   = f2bf(cnt > 0 ? rm : 0.f);
  pooledb[rb_ + 2*DIM + d] = f2bf(ra);
}

// ---------------- small MFMA GEMM: C[M,N] = act(A[M,K] @ Bt[N,K]^T + bias) -> bf16 ----------------
template<int GELU>
__global__ __launch_bounds__(256) void gemm64(const short* __restrict__ A, const short* __restrict__ Bt,
    const float* __restrict__ bias, short* __restrict__ Cout, int K, int ldc){
  __shared__ short lA[64][40];
  __shared__ short lB[64][40];
  int tid = threadIdx.x;
  int wave = tid >> 6, lane = tid & 63;
  int wm = wave >> 1, wn = wave & 1;
  int rb = blockIdx.x * 64, cb = blockIdx.y * 64;
  int l15 = lane & 15, lg = lane >> 4;
  f32x4 acc[2][2] = {};
  int srow = tid >> 2, skg = tid & 3;
  for (int ks = 0; ks < K; ks += 32){
    __syncthreads();
    *(short8*)&lA[srow][skg*8] = *(const short8*)(A  + (size_t)(rb+srow)*K + ks + skg*8);
    *(short8*)&lB[srow][skg*8] = *(const short8*)(Bt + (size_t)(cb+srow)*K + ks + skg*8);
    __syncthreads();
    short8 af[2], bf[2];
#pragma unroll
    for (int f = 0; f < 2; ++f){
      af[f] = *(const short8*)&lA[wm*32 + f*16 + l15][lg*8];
      bf[f] = *(const short8*)&lB[wn*32 + f*16 + l15][lg*8];
    }
#pragma unroll
    for (int fm = 0; fm < 2; ++fm)
#pragma unroll
      for (int fn = 0; fn < 2; ++fn)
        acc[fm][fn] = __builtin_amdgcn_mfma_f32_16x16x32_bf16(af[fm], bf[fn], acc[fm][fn], 0, 0, 0);
  }
#pragma unroll
  for (int fm = 0; fm < 2; ++fm)
#pragma unroll
    for (int fn = 0; fn < 2; ++fn){
      int col = cb + wn*32 + fn*16 + l15;
      float bcv = bias[col];
#pragma unroll
      for (int r = 0; r < 4; ++r){
        int row = rb + wm*32 + fm*16 + lg*4 + r;
        float v = acc[fm][fn][r] + bcv;
        if (GELU) v = 0.5f * v * (1.0f + erff(v * 0.70710678118f));
        Cout[(size_t)row*ldc + col] = f2bf(v);
      }
    }
}

// ---------------- K5: out = [gather(lf, seg) | feats] @ Wc + bc ----------------
// block: 128 rows x 256 cols (full N), 8 waves (2x4), wave tile 64x64 = 4x4 frags
__global__ __launch_bounds__(512) void k5_final(const float* __restrict__ feats, const short* __restrict__ lfb,
    const int* __restrict__ seg, const short* __restrict__ Wct, const float* __restrict__ bc,
    float* __restrict__ out){
  __shared__ short lA[128][72];
  __shared__ short lB[256][72];
  int tid = threadIdx.x;
  int wave = tid >> 6, lane = tid & 63;
  int wm = wave >> 2, wn = wave & 3;
  int rb = blockIdx.x * 128;
  int l15 = lane & 15, lg = lane >> 4;
  f32x4 acc[4][4] = {};
  for (int ks = 0; ks < 8; ++ks){
    __syncthreads();
    // stage A: 128 rows x 64 k (bf16). k<256 -> gathered layer_feats; k>=256 -> feats (f32->bf16)
#pragma unroll
    for (int i = 0; i < 2; ++i){
      int slot = tid + i*512;
      int row = slot >> 3, kg = slot & 7;
      short8 v;
      if (ks < 4){
        int sg = seg[rb + row];
        v = *(const short8*)(lfb + (size_t)sg*DIM + ks*64 + kg*8);
      } else {
        const float* fp = feats + (size_t)(rb+row)*DIM + (ks-4)*64 + kg*8;
        float4 u0 = *(const float4*)fp;
        float4 u1 = *(const float4*)(fp+4);
        short8 t;
        t[0]=f2bf(u0.x); t[1]=f2bf(u0.y); t[2]=f2bf(u0.z); t[3]=f2bf(u0.w);
        t[4]=f2bf(u1.x); t[5]=f2bf(u1.y); t[6]=f2bf(u1.z); t[7]=f2bf(u1.w);
        v = t;
      }
      *(short8*)&lA[row][kg*8] = v;
    }
    // stage B: 256 n-rows x 64 k from Wct [256][512]
#pragma unroll
    for (int i = 0; i < 4; ++i){
      int slot = tid + i*512;
      int n = slot >> 3, kg = slot & 7;
      *(short8*)&lB[n][kg*8] = *(const short8*)(Wct + (size_t)n*K2D + ks*64 + kg*8);
    }
    __syncthreads();
#pragma unroll
    for (int kk = 0; kk < 2; ++kk){
      short8 af[4], bf[4];
#pragma unroll
      for (int f = 0; f < 4; ++f){
        af[f] = *(const short8*)&lA[wm*64 + f*16 + l15][kk*32 + lg*8];
        bf[f] = *(const short8*)&lB[wn*64 + f*16 + l15][kk*32 + lg*8];
      }
#pragma unroll
      for (int fm = 0; fm < 4; ++fm)
#pragma unroll
        for (int fn = 0; fn < 4; ++fn)
          acc[fm][fn] = __builtin_amdgcn_mfma_f32_16x16x32_bf16(af[fm], bf[fn], acc[fm][fn], 0, 0, 0);
    }
  }
#pragma unroll
  for (int fm = 0; fm < 4; ++fm)
#pragma unroll
    for (int fn = 0; fn < 4; ++fn){
      int col = wn*64 + fn*16 + l15;
      float bcv = bc[col];
#pragma unroll
      for (int r = 0; r < 4; ++r){
        int row = rb + wm*64 + fm*16 + lg*4 + r;
        out[(size_t)row*DIM + col] = acc[fm][fn][r] + bcv;
      }
    }
}

extern "C" void kernel_launch(void* const* d_in, const int* in_sizes, int n_in,
                              void* d_out, int out_size, void* d_ws, size_t ws_size,
                              hipStream_t stream){
  const float* feats     = (const float*)d_in[0];
  const int*   cu        = (const int*)d_in[1];
  const int*   layer_ids = (const int*)d_in[2];
  const float* Wa        = (const float*)d_in[3];
  const float* ba        = (const float*)d_in[4];
  const float* W1        = (const float*)d_in[5];
  const float* b1        = (const float*)d_in[6];
  const float* W2        = (const float*)d_in[7];
  const float* b2        = (const float*)d_in[8];
  const float* Wc        = (const float*)d_in[9];
  const float* bc        = (const float*)d_in[10];
  float* out = (float*)d_out;

  char* w = (char*)d_ws;
  auto alloc = [&](size_t bytes)->char*{ char* p = w; w += (bytes + 255) & ~255ull; return p; };
  float*    logits  = (float*)   alloc((size_t)NTOK*4);
  float*    evals   = (float*)   alloc((size_t)NTOK*4);
  int*      seg     = (int*)     alloc((size_t)NTOK*4);
  int*      sorted  = (int*)     alloc((size_t)NTOK*4);
  int*      hist    = (int*)     alloc((size_t)NSEG*HB*4);
  int*      segstart= (int*)     alloc((size_t)(NSEG+1)*4);
  unsigned* bmax    = (unsigned*)alloc(NB*4);
  float*    bz      = (float*)   alloc(NB*4);
  short*    W1t     = (short*)   alloc((size_t)512*768*2);
  short*    W2t     = (short*)   alloc((size_t)256*512*2);
  short*    Wct     = (short*)   alloc((size_t)256*512*2);
  short*    pooledb = (short*)   alloc((size_t)NSEG*K3D*2);
  short*    hb      = (short*)   alloc((size_t)NSEG*EDIM*2);
  short*    lfb     = (short*)   alloc((size_t)NSEG*DIM*2);

  k0_transpose<<<dim3(160), dim3(256), 0, stream>>>(W1, W2, Wc, W1t, W2t, Wct, bmax);
  k1_logits<<<dim3(2048), dim3(256), 0, stream>>>(feats, cu, layer_ids, Wa, ba, logits, seg, bmax);
  k2_softmax_z<<<dim3(16), dim3(256), 0, stream>>>(logits, cu, bmax, evals, bz);
  k3a_hist<<<dim3(HB), dim3(256), 0, stream>>>(seg, hist);
  k3b_scan<<<dim3(1), dim3(1024), 0, stream>>>(hist, segstart);
  k3c_scatter<<<dim3(HB), dim3(256), 0, stream>>>(seg, hist, sorted);
  k4_pool<<<dim3(NSEG), dim3(256), 0, stream>>>(feats, sorted, segstart, evals, bz, pooledb);
  gemm64<1><<<dim3(16, 8), dim3(256), 0, stream>>>(pooledb, W1t, b1, hb, 768, 512);
  gemm64<0><<<dim3(16, 4), dim3(256), 0, stream>>>(hb, W2t, b2, lfb, 512, 256);
  k5_final<<<dim3(1024), dim3(512), 0, stream>>>(feats, lfb, seg, Wct, bc, out);
}